// Round 3
// baseline (2006.085 us; speedup 1.0000x reference)
//
#include <hip/hip_runtime.h>
#include <hip/hip_bf16.h>

// Flash attention fwd, B=4 H=16 S=2048 D=128. fp32 in/out.
// Round-6: same per-wave compute as the 532us round-5 kernel (prepacked bf16
// K hi/lo + V^T in d_ws, reg-prefetch staging, PK=136/PVT=40 LDS layouts,
// split-bf16 QK^T, exp2 online softmax) but 8-wave blocks: BM=128, 512 thr.
// VGPR/wave is 64 -> 8 waves/SIMD legal; LDS 37.9 KB -> still 4 blocks/CU
// -> 32 waves/CU (100% occupancy, was 16) and grid=1024 = exactly 4/CU in
// ONE pass (was 2 ragged passes of 2048). Per-thread staging halves
// (3 chunks). T5 setprio(1) around MFMA clusters (8-wave phase diversity).

typedef __bf16 bf16;
typedef __attribute__((ext_vector_type(4))) __bf16 bf16x4;
typedef __attribute__((ext_vector_type(8))) __bf16 bf16x8;
typedef __attribute__((ext_vector_type(4))) float f32x4;

constexpr int S_  = 2048;
constexpr int D_  = 128;
constexpr int BM  = 128;      // Q rows per block (8 waves x 16)
constexpr int BN  = 32;       // K/V rows per tile
constexpr int NIT = S_ / BN;  // 64
constexpr int PK  = D_ + 8;   // 136 bf16 K pitch
constexpr int PVT = BN + 8;   // 40 bf16 V^T pitch
constexpr int PP  = BN + 8;   // 40 bf16 P pitch

// bf16-element offsets of the packed images inside d_ws
constexpr size_t WS_KL   = 16777216;   // Klo image at +32 MB
constexpr size_t WS_VT   = 33554432;   // V^T image at +64 MB
constexpr size_t WS_NEED = 100663296;  // 96 MB total (bytes)

// ---- pre-pack ----
// Kh/Kl images: [head][s][d] bf16, pitch 128 (tile it = 4096-elem block).
// V^T image: [head][tile][d][32] bf16 (per (head,tile) 4096 elems).
__global__ __launch_bounds__(256) void prepack(
    const float* __restrict__ kg, const float* __restrict__ vg,
    bf16* __restrict__ ws)
{
    const int gid = blockIdx.x * 256 + threadIdx.x;
    if (gid < 2097152) {                  // K: (64*2048 rows) x 16 chunks
        const int u  = gid & 15;
        const int rg = gid >> 4;          // head*2048 + s
        const float* src = kg + (size_t)rg * D_ + (u << 3);
        float x[8];
        *(float4*)&x[0] = *(const float4*)src;
        *(float4*)&x[4] = *(const float4*)(src + 4);
        bf16x8 h8, l8;
#pragma unroll
        for (int j = 0; j < 8; ++j) {
            bf16 h = (bf16)x[j];
            h8[j] = h;
            l8[j] = (bf16)(x[j] - (float)h);
        }
        const size_t di = (size_t)rg * 128 + (u << 3);
        *(bf16x8*)&ws[di]         = h8;
        *(bf16x8*)&ws[WS_KL + di] = l8;
    } else {                              // V: 4096 (head,tile) x 512 tasks
        const int g2 = gid - 2097152;
        const int i  = g2 & 511;
        const int tg = g2 >> 9;           // head*64 + tile
        const int p  = i & 15;            // t-pair: rows 2p, 2p+1
        const int c  = i >> 4;            // 0..31: cols 4c..4c+3
        const float* src = vg + ((size_t)tg * BN + 2 * p) * D_ + c * 4;
        float4 a0 = *(const float4*)src;
        float4 a1 = *(const float4*)(src + D_);
        const float* x0 = (const float*)&a0;
        const float* x1 = (const float*)&a1;
        bf16* vt = ws + WS_VT + (size_t)tg * 4096;
#pragma unroll
        for (int j = 0; j < 4; ++j) {
            union { ushort2 u2; bf16 b[2]; } pr;
            pr.b[0] = (bf16)x0[j];
            pr.b[1] = (bf16)x1[j];
            *(ushort2*)&vt[(c * 4 + j) * BN + 2 * p] = pr.u2;
        }
    }
}

// ---- main kernel: 8 waves x 16 Q-rows, 4 blocks/CU, 32 waves/CU ----
__global__ __launch_bounds__(512, 8) void attn_fwd(
    const float* __restrict__ q, const bf16* __restrict__ ws,
    const float* __restrict__ sc, float* __restrict__ out)
{
    __shared__ __align__(16) bf16 Kh[BN * PK];      // 8704 B
    __shared__ __align__(16) bf16 Kl[BN * PK];      // 8704 B
    __shared__ __align__(16) bf16 Vs[D_ * PVT];     // 10240 B (Vs[d][t])
    __shared__ __align__(16) bf16 Ps[8 * 16 * PP];  // 10240 B (wave-private)
    // total 37888 B -> 4 blocks/CU

    const int tid  = threadIdx.x;
    const int wave = tid >> 6;
    const int lane = tid & 63;
    const int l16  = lane & 15;
    const int quad = lane >> 4;

    // head-affinity XCD swizzle: 1024 blocks; XCD (bid&7) gets heads 8x..8x+7
    const int bid = blockIdx.x;
    const int idx = bid >> 3;                        // 0..127
    const int bh  = ((bid & 7) << 3) | (idx >> 4);   // head 0..63
    const int qt  = idx & 15;                        // Q tile 0..15 (128 rows)

    const float scale = sc[bh] * 1.44269504088896f;  // fold log2(e)

    const float* qbase = q + ((size_t)bh * S_ + (size_t)qt * BM) * D_;
    const bf16* khp = ws +         (size_t)bh * 262144 + tid * 8;
    const bf16* klp = ws + WS_KL + (size_t)bh * 262144 + tid * 8;
    const bf16* vtp = ws + WS_VT + (size_t)bh * 262144 + tid * 8;

    // Q fragments (A-layout: m=l16, k=quad*8+j, +32*ks), scale folded, hi/lo
    bf16x8 qh[4], ql[4];
    {
        const float* qrow = qbase + (size_t)(wave * 16 + l16) * D_ + quad * 8;
#pragma unroll
        for (int ks = 0; ks < 4; ++ks) {
            float x[8];
            *(float4*)&x[0] = *(const float4*)(qrow + ks * 32);
            *(float4*)&x[4] = *(const float4*)(qrow + ks * 32 + 4);
#pragma unroll
            for (int j = 0; j < 8; ++j) {
                float xs = x[j] * scale;
                bf16 h = (bf16)xs;
                qh[ks][j] = h;
                ql[ks][j] = (bf16)(xs - (float)h);
            }
        }
    }

    f32x4 O[8];                  // O[dblk][r]: row=quad*4+r, col=l16+16*dblk
#pragma unroll
    for (int i = 0; i < 8; ++i) O[i] = (f32x4){0.f, 0.f, 0.f, 0.f};
    float mrow[4] = {-1e30f, -1e30f, -1e30f, -1e30f};
    float Lp[4]   = {0.f, 0.f, 0.f, 0.f};   // per-lane partial row sums

    // prefetch registers: 3 x 16 B held across one full compute phase
    bf16x8 rKh, rKl, rVt;

#define LOADT(t)                                                          \
    {                                                                     \
        const size_t toff = (size_t)(t) * 4096;                           \
        rKh = *(const bf16x8*)(khp + toff);                               \
        rKl = *(const bf16x8*)(klp + toff);                               \
        rVt = *(const bf16x8*)(vtp + toff);                               \
    }

#define WRITET()                                                          \
    {                                                                     \
        *(bf16x8*)&Kh[(tid >> 4) * PK + (tid & 15) * 8] = rKh;            \
        *(bf16x8*)&Kl[(tid >> 4) * PK + (tid & 15) * 8] = rKl;            \
        *(bf16x8*)&Vs[(tid >> 2) * PVT + (tid & 3) * 8] = rVt;            \
    }

    // prologue: tile 0 -> LDS, tile 1 in flight
    LOADT(0);
    WRITET();
    LOADT(1);
    __syncthreads();

    for (int it = 0; it < NIT; ++it) {
        // ---- QK^T: S[16 x 32] per wave, split-bf16 ----
        f32x4 sacc[2];
        sacc[0] = (f32x4){0.f, 0.f, 0.f, 0.f};
        sacc[1] = (f32x4){0.f, 0.f, 0.f, 0.f};
        __builtin_amdgcn_s_setprio(1);
#pragma unroll
        for (int ks = 0; ks < 4; ++ks) {
#pragma unroll
            for (int nb = 0; nb < 2; ++nb) {
                int off = (nb * 16 + l16) * PK + ks * 32 + quad * 8;
                bf16x8 kh = *(const bf16x8*)&Kh[off];
                bf16x8 kl = *(const bf16x8*)&Kl[off];
                sacc[nb] = __builtin_amdgcn_mfma_f32_16x16x32_bf16(qh[ks], kh, sacc[nb], 0, 0, 0);
                sacc[nb] = __builtin_amdgcn_mfma_f32_16x16x32_bf16(qh[ks], kl, sacc[nb], 0, 0, 0);
                sacc[nb] = __builtin_amdgcn_mfma_f32_16x16x32_bf16(ql[ks], kh, sacc[nb], 0, 0, 0);
            }
        }
        __builtin_amdgcn_s_setprio(0);

        // ---- online softmax (exp2 domain; logits pre-scaled) ----
        float p0[4], p1[4];
#pragma unroll
        for (int r = 0; r < 4; ++r) {
            float m0 = fmaxf(sacc[0][r], sacc[1][r]);
#pragma unroll
            for (int off = 8; off >= 1; off >>= 1)
                m0 = fmaxf(m0, __shfl_xor(m0, off, 64));
            float mnew  = fmaxf(mrow[r], m0);
            float alpha = __builtin_amdgcn_exp2f(mrow[r] - mnew);
            mrow[r] = mnew;
            float e0 = __builtin_amdgcn_exp2f(sacc[0][r] - mnew);
            float e1 = __builtin_amdgcn_exp2f(sacc[1][r] - mnew);
            p0[r] = e0; p1[r] = e1;
            Lp[r] = Lp[r] * alpha + (e0 + e1);   // per-lane partial (2 cols)
#pragma unroll
            for (int d = 0; d < 8; ++d) O[d][r] *= alpha;
        }

        // ---- P: C-layout regs -> wave-private LDS (A-layout read below) ----
        bf16* pw = &Ps[wave * 16 * PP];
#pragma unroll
        for (int r = 0; r < 4; ++r) {
            pw[(quad * 4 + r) * PP + l16]      = (bf16)p0[r];
            pw[(quad * 4 + r) * PP + 16 + l16] = (bf16)p1[r];
        }
        // same-wave DS RAW ordered via lgkmcnt by compiler

        // ---- PV: O[16 x 128] += P[16 x 32] * V[32 x 128] ----
        {
            bf16x8 pa = *(const bf16x8*)&pw[l16 * PP + quad * 8];
            __builtin_amdgcn_s_setprio(1);
#pragma unroll
            for (int d = 0; d < 8; ++d) {
                bf16x8 vb = *(const bf16x8*)&Vs[(d * 16 + l16) * PVT + quad * 8];
                O[d] = __builtin_amdgcn_mfma_f32_16x16x32_bf16(pa, vb, O[d], 0, 0, 0);
            }
            __builtin_amdgcn_s_setprio(0);
        }

        if (it == NIT - 1) break;
        __syncthreads();            // all readers done with current tile
        WRITET();                   // stage tile it+1 (regs loaded last iter)
        if (it + 2 < NIT) LOADT(it + 2);   // in flight across next compute
        __syncthreads();            // tile it+1 visible
    }

    // ---- finalize: reduce per-lane L across the 16 l16-lanes, then store ----
    float rl[4];
#pragma unroll
    for (int r = 0; r < 4; ++r) {
        float L = Lp[r];
#pragma unroll
        for (int off = 8; off >= 1; off >>= 1)
            L += __shfl_xor(L, off, 64);
        rl[r] = 1.0f / L;
    }
    float* og = out + ((size_t)bh * S_ + (size_t)qt * BM + wave * 16) * D_;
#pragma unroll
    for (int d = 0; d < 8; ++d)
#pragma unroll
        for (int r = 0; r < 4; ++r)
            og[(quad * 4 + r) * D_ + d * 16 + l16] = O[d][r] * rl[r];
}

// ---- fallback: round-0 verified kernel (used if ws too small) ----
__global__ __launch_bounds__(256, 4) void attn_fwd_fb(
    const float* __restrict__ q, const float* __restrict__ kg,
    const float* __restrict__ vg, const float* __restrict__ sc,
    float* __restrict__ out)
{
    constexpr int FBM = 64;

    __shared__ __align__(16) bf16 Kh[BN * PK];
    __shared__ __align__(16) bf16 Kl[BN * PK];
    __shared__ __align__(16) bf16 Vs[D_ * PVT];
    __shared__ __align__(16) bf16 Ps2[4 * 16 * PP];

    const int tid  = threadIdx.x;
    const int wave = tid >> 6;
    const int lane = tid & 63;
    const int l16  = lane & 15;
    const int quad = lane >> 4;

    const int qt = blockIdx.x;
    const int bh = blockIdx.y;

    const float scale = sc[bh] * 1.44269504088896f;

    const float* qbase = q  + ((size_t)bh * S_ + (size_t)qt * FBM) * D_;
    const float* kbase = kg + (size_t)bh * S_ * D_;
    const float* vbase = vg + (size_t)bh * S_ * D_;

    bf16x8 qh[4], ql[4];
    {
        const float* qrow = qbase + (size_t)(wave * 16 + l16) * D_ + quad * 8;
#pragma unroll
        for (int ks = 0; ks < 4; ++ks) {
            float x[8];
            *(float4*)&x[0] = *(const float4*)(qrow + ks * 32);
            *(float4*)&x[4] = *(const float4*)(qrow + ks * 32 + 4);
#pragma unroll
            for (int j = 0; j < 8; ++j) {
                float xs = x[j] * scale;
                bf16 h = (bf16)xs;
                qh[ks][j] = h;
                ql[ks][j] = (bf16)(xs - (float)h);
            }
        }
    }

    f32x4 O[8];
#pragma unroll
    for (int i = 0; i < 8; ++i) O[i] = (f32x4){0.f, 0.f, 0.f, 0.f};
    float mrow[4] = {-1e30f, -1e30f, -1e30f, -1e30f};
    float Lp[4]   = {0.f, 0.f, 0.f, 0.f};

    for (int it = 0; it < NIT; ++it) {
        __syncthreads();
        {
            const float* kt = kbase + (size_t)it * BN * D_;
#pragma unroll
            for (int r = 0; r < 4; ++r) {
                int i = tid + r * 256;
                int row = i >> 5, c = i & 31;
                float4 v = *(const float4*)(kt + row * D_ + c * 4);
                const float* x = (const float*)&v;
                bf16x4 h4, l4;
#pragma unroll
                for (int j = 0; j < 4; ++j) {
                    bf16 h = (bf16)x[j];
                    h4[j] = h;
                    l4[j] = (bf16)(x[j] - (float)h);
                }
                *(bf16x4*)&Kh[row * PK + c * 4] = h4;
                *(bf16x4*)&Kl[row * PK + c * 4] = l4;
            }
            const float* vt = vbase + (size_t)it * BN * D_;
#pragma unroll
            for (int r = 0; r < 2; ++r) {
                int i = tid + r * 256;
                int p = i & 15;
                int c = i >> 4;
                const float* v0 = vt + (2 * p) * D_ + c * 4;
                float4 a0 = *(const float4*)v0;
                float4 a1 = *(const float4*)(v0 + D_);
                const float* x0 = (const float*)&a0;
                const float* x1 = (const float*)&a1;
#pragma unroll
                for (int j = 0; j < 4; ++j) {
                    union { ushort2 u; bf16 b[2]; } pr;
                    pr.b[0] = (bf16)x0[j];
                    pr.b[1] = (bf16)x1[j];
                    *(ushort2*)&Vs[(c * 4 + j) * PVT + 2 * p] = pr.u;
                }
            }
        }
        __syncthreads();

        f32x4 sacc[2];
        sacc[0] = (f32x4){0.f, 0.f, 0.f, 0.f};
        sacc[1] = (f32x4){0.f, 0.f, 0.f, 0.f};
#pragma unroll
        for (int ks = 0; ks < 4; ++ks) {
#pragma unroll
            for (int nb = 0; nb < 2; ++nb) {
                int off = (nb * 16 + l16) * PK + ks * 32 + quad * 8;
                bf16x8 kh = *(const bf16x8*)&Kh[off];
                bf16x8 kl = *(const bf16x8*)&Kl[off];
                sacc[nb] = __builtin_amdgcn_mfma_f32_16x16x32_bf16(qh[ks], kh, sacc[nb], 0, 0, 0);
                sacc[nb] = __builtin_amdgcn_mfma_f32_16x16x32_bf16(qh[ks], kl, sacc[nb], 0, 0, 0);
                sacc[nb] = __builtin_amdgcn_mfma_f32_16x16x32_bf16(ql[ks], kh, sacc[nb], 0, 0, 0);
            }
        }

        float p0[4], p1[4];
#pragma unroll
        for (int r = 0; r < 4; ++r) {
            float m0 = fmaxf(sacc[0][r], sacc[1][r]);
#pragma unroll
            for (int off = 8; off >= 1; off >>= 1)
                m0 = fmaxf(m0, __shfl_xor(m0, off, 64));
            float mnew  = fmaxf(mrow[r], m0);
            float alpha = __builtin_amdgcn_exp2f(mrow[r] - mnew);
            mrow[r] = mnew;
            float e0 = __builtin_amdgcn_exp2f(sacc[0][r] - mnew);
            float e1 = __builtin_amdgcn_exp2f(sacc[1][r] - mnew);
            p0[r] = e0; p1[r] = e1;
            Lp[r] = Lp[r] * alpha + (e0 + e1);
#pragma unroll
            for (int d = 0; d < 8; ++d) O[d][r] *= alpha;
        }

        bf16* pw = &Ps2[wave * 16 * PP];
#pragma unroll
        for (int r = 0; r < 4; ++r) {
            pw[(quad * 4 + r) * PP + l16]      = (bf16)p0[r];
            pw[(quad * 4 + r) * PP + 16 + l16] = (bf16)p1[r];
        }
        {
            bf16x8 pa = *(const bf16x8*)&pw[l16 * PP + quad * 8];
#pragma unroll
            for (int d = 0; d < 8; ++d) {
                bf16x8 vb = *(const bf16x8*)&Vs[(d * 16 + l16) * PVT + quad * 8];
                O[d] = __builtin_amdgcn_mfma_f32_16x16x32_bf16(pa, vb, O[d], 0, 0, 0);
            }
        }
    }

    float rl[4];
#pragma unroll
    for (int r = 0; r < 4; ++r) {
        float L = Lp[r];
#pragma unroll
        for (int off = 8; off >= 1; off >>= 1)
            L += __shfl_xor(L, off, 64);
        rl[r] = 1.0f / L;
    }
    float* og = out + ((size_t)bh * S_ + (size_t)qt * FBM + wave * 16) * D_;
#pragma unroll
    for (int d = 0; d < 8; ++d)
#pragma unroll
        for (int r = 0; r < 4; ++r)
            og[(quad * 4 + r) * D_ + d * 16 + l16] = O[d][r] * rl[r];
}

extern "C" void kernel_launch(void* const* d_in, const int* in_sizes, int n_in,
                              void* d_out, int out_size, void* d_ws, size_t ws_size,
                              hipStream_t stream) {
    const float* q  = (const float*)d_in[0];
    const float* k  = (const float*)d_in[1];
    const float* v  = (const float*)d_in[2];
    const float* sc = (const float*)d_in[3];
    float* o = (float*)d_out;
    if (d_ws && ws_size >= WS_NEED) {
        bf16* ws = (bf16*)d_ws;
        prepack<<<16384, 256, 0, stream>>>(k, v, ws);          // ~60 us
        attn_fwd<<<1024, 512, 0, stream>>>(q, ws, sc, o);
    } else {
        attn_fwd_fb<<<dim3(S_ / 64, 64), 256, 0, stream>>>(q, k, v, sc, o);
    }
}

// Round 4
// 610.267 us; speedup vs baseline: 3.2872x; 3.2872x over previous
//
#include <hip/hip_runtime.h>
#include <hip/hip_bf16.h>

// Flash attention fwd, B=4 H=16 S=2048 D=128. fp32 in/out.
// Round-7: revert to the verified 532us round-5/6 structure (256 threads,
// 4 waves x 16 Q-rows, BM=64, launch_bounds(256,4) -> VGPR 64, no spills;
// round-3's 512-thread/8-wave variant forced a 64-VGPR cap and spilled:
// WRITE_SIZE 3.3 GB scratch traffic, 1830us). Additions on top, both
// low-register-cost and measured-positive on attn:
//   T5: s_setprio(1) around the QK^T and PV MFMA clusters (+4-7%, m191).
//   T13: defer-max online softmax (THR=8 in exp2 domain): skip the
//        O-rescale pass when no row's tile-max grew by >8 (+5%, m214v23).
// Everything else bit-identical: prepacked bf16 K hi/lo + V^T in d_ws,
// reg-prefetch staging, PK=136/PVT=40 LDS layouts, split-bf16 QK^T
// (qh*kh+qh*kl+ql*kh), exp2-domain online softmax, head-affinity XCD swizzle.

typedef __bf16 bf16;
typedef __attribute__((ext_vector_type(4))) __bf16 bf16x4;
typedef __attribute__((ext_vector_type(8))) __bf16 bf16x8;
typedef __attribute__((ext_vector_type(4))) float f32x4;

constexpr int S_  = 2048;
constexpr int D_  = 128;
constexpr int BM  = 64;       // Q rows per block (4 waves x 16)
constexpr int BN  = 32;       // K/V rows per tile
constexpr int NIT = S_ / BN;  // 64
constexpr int PK  = D_ + 8;   // 136 bf16 K pitch
constexpr int PVT = BN + 8;   // 40 bf16 V^T pitch
constexpr int PP  = BN + 8;   // 40 bf16 P pitch

// bf16-element offsets of the packed images inside d_ws
constexpr size_t WS_KL   = 16777216;   // Klo image at +32 MB
constexpr size_t WS_VT   = 33554432;   // V^T image at +64 MB
constexpr size_t WS_NEED = 100663296;  // 96 MB total (bytes)

// ---- pre-pack ----
// Kh/Kl images: [head][s][d] bf16, pitch 128 (tile it = 4096-elem block).
// V^T image: [head][tile][d][32] bf16 (per (head,tile) 4096 elems).
__global__ __launch_bounds__(256) void prepack(
    const float* __restrict__ kg, const float* __restrict__ vg,
    bf16* __restrict__ ws)
{
    const int gid = blockIdx.x * 256 + threadIdx.x;
    if (gid < 2097152) {                  // K: (64*2048 rows) x 16 chunks
        const int u  = gid & 15;
        const int rg = gid >> 4;          // head*2048 + s
        const float* src = kg + (size_t)rg * D_ + (u << 3);
        float x[8];
        *(float4*)&x[0] = *(const float4*)src;
        *(float4*)&x[4] = *(const float4*)(src + 4);
        bf16x8 h8, l8;
#pragma unroll
        for (int j = 0; j < 8; ++j) {
            bf16 h = (bf16)x[j];
            h8[j] = h;
            l8[j] = (bf16)(x[j] - (float)h);
        }
        const size_t di = (size_t)rg * 128 + (u << 3);
        *(bf16x8*)&ws[di]         = h8;
        *(bf16x8*)&ws[WS_KL + di] = l8;
    } else {                              // V: 4096 (head,tile) x 512 tasks
        const int g2 = gid - 2097152;
        const int i  = g2 & 511;
        const int tg = g2 >> 9;           // head*64 + tile
        const int p  = i & 15;            // t-pair: rows 2p, 2p+1
        const int c  = i >> 4;            // 0..31: cols 4c..4c+3
        const float* src = vg + ((size_t)tg * BN + 2 * p) * D_ + c * 4;
        float4 a0 = *(const float4*)src;
        float4 a1 = *(const float4*)(src + D_);
        const float* x0 = (const float*)&a0;
        const float* x1 = (const float*)&a1;
        bf16* vt = ws + WS_VT + (size_t)tg * 4096;
#pragma unroll
        for (int j = 0; j < 4; ++j) {
            union { ushort2 u2; bf16 b[2]; } pr;
            pr.b[0] = (bf16)x0[j];
            pr.b[1] = (bf16)x1[j];
            *(ushort2*)&vt[(c * 4 + j) * BN + 2 * p] = pr.u2;
        }
    }
}

// ---- main kernel: 4 waves x 16 Q-rows, 32 KB LDS -> 4 blocks/CU ----
__global__ __launch_bounds__(256, 4) void attn_fwd(
    const float* __restrict__ q, const bf16* __restrict__ ws,
    const float* __restrict__ sc, float* __restrict__ out)
{
    __shared__ __align__(16) bf16 Kh[BN * PK];      // 8704 B
    __shared__ __align__(16) bf16 Kl[BN * PK];      // 8704 B
    __shared__ __align__(16) bf16 Vs[D_ * PVT];     // 10240 B (Vs[d][t])
    __shared__ __align__(16) bf16 Ps[4 * 16 * PP];  // 5120 B (wave-private)
    // total 32768 B -> 4 blocks/CU, 16 waves/CU

    const int tid  = threadIdx.x;
    const int wave = tid >> 6;
    const int lane = tid & 63;
    const int l16  = lane & 15;
    const int quad = lane >> 4;

    // head-affinity XCD swizzle: 2048 blocks; XCD (bid&7) gets heads 8x..8x+7
    const int bid = blockIdx.x;
    const int idx = bid >> 3;                        // 0..255
    const int bh  = ((bid & 7) << 3) | (idx >> 5);   // head 0..63
    const int qt  = idx & 31;                        // Q tile 0..31

    const float scale = sc[bh] * 1.44269504088896f;  // fold log2(e)

    const float* qbase = q + ((size_t)bh * S_ + (size_t)qt * BM) * D_;
    const bf16* khp = ws +         (size_t)bh * 262144 + tid * 8;
    const bf16* klp = ws + WS_KL + (size_t)bh * 262144 + tid * 8;
    const bf16* vtp = ws + WS_VT + (size_t)bh * 262144 + tid * 8;

    // Q fragments (A-layout: m=l16, k=quad*8+j, +32*ks), scale folded, hi/lo
    bf16x8 qh[4], ql[4];
    {
        const float* qrow = qbase + (size_t)(wave * 16 + l16) * D_ + quad * 8;
#pragma unroll
        for (int ks = 0; ks < 4; ++ks) {
            float x[8];
            *(float4*)&x[0] = *(const float4*)(qrow + ks * 32);
            *(float4*)&x[4] = *(const float4*)(qrow + ks * 32 + 4);
#pragma unroll
            for (int j = 0; j < 8; ++j) {
                float xs = x[j] * scale;
                bf16 h = (bf16)xs;
                qh[ks][j] = h;
                ql[ks][j] = (bf16)(xs - (float)h);
            }
        }
    }

    f32x4 O[8];                  // O[dblk][r]: row=quad*4+r, col=l16+16*dblk
#pragma unroll
    for (int i = 0; i < 8; ++i) O[i] = (f32x4){0.f, 0.f, 0.f, 0.f};
    float mrow[4] = {-1e30f, -1e30f, -1e30f, -1e30f};
    float Lp[4]   = {0.f, 0.f, 0.f, 0.f};   // per-lane partial row sums

    // prefetch registers: 6 x 16 B held across one full compute phase
    bf16x8 rKh[2], rKl[2], rVt[2];

#define LOADT(t)                                                          \
    {                                                                     \
        const size_t toff = (size_t)(t) * 4096;                           \
        rKh[0] = *(const bf16x8*)(khp + toff);                            \
        rKh[1] = *(const bf16x8*)(khp + toff + 2048);                     \
        rKl[0] = *(const bf16x8*)(klp + toff);                            \
        rKl[1] = *(const bf16x8*)(klp + toff + 2048);                     \
        rVt[0] = *(const bf16x8*)(vtp + toff);                            \
        rVt[1] = *(const bf16x8*)(vtp + toff + 2048);                     \
    }

#define WRITET()                                                          \
    {                                                                     \
        _Pragma("unroll")                                                 \
        for (int j = 0; j < 2; ++j) {                                     \
            int i = tid + j * 256;                                        \
            *(bf16x8*)&Kh[(i >> 4) * PK + (i & 15) * 8] = rKh[j];         \
            *(bf16x8*)&Kl[(i >> 4) * PK + (i & 15) * 8] = rKl[j];         \
            *(bf16x8*)&Vs[(i >> 2) * PVT + (i & 3) * 8] = rVt[j];         \
        }                                                                 \
    }

    // prologue: tile 0 -> LDS, tile 1 in flight
    LOADT(0);
    WRITET();
    LOADT(1);
    __syncthreads();

    for (int it = 0; it < NIT; ++it) {
        // ---- QK^T: S[16 x 32] per wave, split-bf16 ----
        f32x4 sacc[2];
        sacc[0] = (f32x4){0.f, 0.f, 0.f, 0.f};
        sacc[1] = (f32x4){0.f, 0.f, 0.f, 0.f};
        __builtin_amdgcn_s_setprio(1);
#pragma unroll
        for (int ks = 0; ks < 4; ++ks) {
#pragma unroll
            for (int nb = 0; nb < 2; ++nb) {
                int off = (nb * 16 + l16) * PK + ks * 32 + quad * 8;
                bf16x8 kh = *(const bf16x8*)&Kh[off];
                bf16x8 kl = *(const bf16x8*)&Kl[off];
                sacc[nb] = __builtin_amdgcn_mfma_f32_16x16x32_bf16(qh[ks], kh, sacc[nb], 0, 0, 0);
                sacc[nb] = __builtin_amdgcn_mfma_f32_16x16x32_bf16(qh[ks], kl, sacc[nb], 0, 0, 0);
                sacc[nb] = __builtin_amdgcn_mfma_f32_16x16x32_bf16(ql[ks], kh, sacc[nb], 0, 0, 0);
            }
        }
        __builtin_amdgcn_s_setprio(0);

        // ---- online softmax (exp2 domain, defer-max THR=8) ----
        // Row-max reduce is over the 16 l16-lanes (cols of the row live at
        // fixed quad): xor offsets 8..1 suffice; m0 is uniform per 16-group.
        float m0r[4];
        bool grow = false;
#pragma unroll
        for (int r = 0; r < 4; ++r) {
            float m0 = fmaxf(sacc[0][r], sacc[1][r]);
#pragma unroll
            for (int off = 8; off >= 1; off >>= 1)
                m0 = fmaxf(m0, __shfl_xor(m0, off, 64));
            m0r[r] = m0;
            grow |= (m0 - mrow[r] > 8.0f);
        }
        if (__any(grow)) {
            // full rescale path (rare after the first few tiles)
#pragma unroll
            for (int r = 0; r < 4; ++r) {
                float mnew  = fmaxf(mrow[r], m0r[r]);
                float alpha = __builtin_amdgcn_exp2f(mrow[r] - mnew);
                mrow[r] = mnew;
                Lp[r] *= alpha;
#pragma unroll
                for (int d = 0; d < 8; ++d) O[d][r] *= alpha;
            }
        }
        float p0[4], p1[4];
#pragma unroll
        for (int r = 0; r < 4; ++r) {
            float e0 = __builtin_amdgcn_exp2f(sacc[0][r] - mrow[r]);
            float e1 = __builtin_amdgcn_exp2f(sacc[1][r] - mrow[r]);
            p0[r] = e0; p1[r] = e1;
            Lp[r] += e0 + e1;            // per-lane partial (2 cols)
        }

        // ---- P: C-layout regs -> wave-private LDS (A-layout read below) ----
        bf16* pw = &Ps[wave * 16 * PP];
#pragma unroll
        for (int r = 0; r < 4; ++r) {
            pw[(quad * 4 + r) * PP + l16]      = (bf16)p0[r];
            pw[(quad * 4 + r) * PP + 16 + l16] = (bf16)p1[r];
        }
        // same-wave DS RAW ordered via lgkmcnt by compiler

        // ---- PV: O[16 x 128] += P[16 x 32] * V[32 x 128] ----
        {
            bf16x8 pa = *(const bf16x8*)&pw[l16 * PP + quad * 8];
            __builtin_amdgcn_s_setprio(1);
#pragma unroll
            for (int d = 0; d < 8; ++d) {
                bf16x8 vb = *(const bf16x8*)&Vs[(d * 16 + l16) * PVT + quad * 8];
                O[d] = __builtin_amdgcn_mfma_f32_16x16x32_bf16(pa, vb, O[d], 0, 0, 0);
            }
            __builtin_amdgcn_s_setprio(0);
        }

        if (it == NIT - 1) break;
        __syncthreads();            // all readers done with current tile
        WRITET();                   // stage tile it+1 (regs loaded last iter)
        if (it + 2 < NIT) LOADT(it + 2);   // in flight across next compute
        __syncthreads();            // tile it+1 visible
    }

    // ---- finalize: reduce per-lane L across the 16 l16-lanes, then store ----
    float rl[4];
#pragma unroll
    for (int r = 0; r < 4; ++r) {
        float L = Lp[r];
#pragma unroll
        for (int off = 8; off >= 1; off >>= 1)
            L += __shfl_xor(L, off, 64);
        rl[r] = 1.0f / L;
    }
    float* og = out + ((size_t)bh * S_ + (size_t)qt * BM + wave * 16) * D_;
#pragma unroll
    for (int d = 0; d < 8; ++d)
#pragma unroll
        for (int r = 0; r < 4; ++r)
            og[(quad * 4 + r) * D_ + d * 16 + l16] = O[d][r] * rl[r];
}

// ---- fallback: round-0 verified kernel (used if ws too small) ----
__global__ __launch_bounds__(256, 4) void attn_fwd_fb(
    const float* __restrict__ q, const float* __restrict__ kg,
    const float* __restrict__ vg, const float* __restrict__ sc,
    float* __restrict__ out)
{
    __shared__ __align__(16) bf16 Kh[BN * PK];
    __shared__ __align__(16) bf16 Kl[BN * PK];
    __shared__ __align__(16) bf16 Vs[D_ * PVT];
    __shared__ __align__(16) bf16 Ps2[4 * 16 * PP];

    const int tid  = threadIdx.x;
    const int wave = tid >> 6;
    const int lane = tid & 63;
    const int l16  = lane & 15;
    const int quad = lane >> 4;

    const int qt = blockIdx.x;
    const int bh = blockIdx.y;

    const float scale = sc[bh] * 1.44269504088896f;

    const float* qbase = q  + ((size_t)bh * S_ + (size_t)qt * BM) * D_;
    const float* kbase = kg + (size_t)bh * S_ * D_;
    const float* vbase = vg + (size_t)bh * S_ * D_;

    bf16x8 qh[4], ql[4];
    {
        const float* qrow = qbase + (size_t)(wave * 16 + l16) * D_ + quad * 8;
#pragma unroll
        for (int ks = 0; ks < 4; ++ks) {
            float x[8];
            *(float4*)&x[0] = *(const float4*)(qrow + ks * 32);
            *(float4*)&x[4] = *(const float4*)(qrow + ks * 32 + 4);
#pragma unroll
            for (int j = 0; j < 8; ++j) {
                float xs = x[j] * scale;
                bf16 h = (bf16)xs;
                qh[ks][j] = h;
                ql[ks][j] = (bf16)(xs - (float)h);
            }
        }
    }

    f32x4 O[8];
#pragma unroll
    for (int i = 0; i < 8; ++i) O[i] = (f32x4){0.f, 0.f, 0.f, 0.f};
    float mrow[4] = {-1e30f, -1e30f, -1e30f, -1e30f};
    float Lp[4]   = {0.f, 0.f, 0.f, 0.f};

    for (int it = 0; it < NIT; ++it) {
        __syncthreads();
        {
            const float* kt = kbase + (size_t)it * BN * D_;
#pragma unroll
            for (int r = 0; r < 4; ++r) {
                int i = tid + r * 256;
                int row = i >> 5, c = i & 31;
                float4 v = *(const float4*)(kt + row * D_ + c * 4);
                const float* x = (const float*)&v;
                bf16x4 h4, l4;
#pragma unroll
                for (int j = 0; j < 4; ++j) {
                    bf16 h = (bf16)x[j];
                    h4[j] = h;
                    l4[j] = (bf16)(x[j] - (float)h);
                }
                *(bf16x4*)&Kh[row * PK + c * 4] = h4;
                *(bf16x4*)&Kl[row * PK + c * 4] = l4;
            }
            const float* vt = vbase + (size_t)it * BN * D_;
#pragma unroll
            for (int r = 0; r < 2; ++r) {
                int i = tid + r * 256;
                int p = i & 15;
                int c = i >> 4;
                const float* v0 = vt + (2 * p) * D_ + c * 4;
                float4 a0 = *(const float4*)v0;
                float4 a1 = *(const float4*)(v0 + D_);
                const float* x0 = (const float*)&a0;
                const float* x1 = (const float*)&a1;
#pragma unroll
                for (int j = 0; j < 4; ++j) {
                    union { ushort2 u; bf16 b[2]; } pr;
                    pr.b[0] = (bf16)x0[j];
                    pr.b[1] = (bf16)x1[j];
                    *(ushort2*)&Vs[(c * 4 + j) * PVT + 2 * p] = pr.u;
                }
            }
        }
        __syncthreads();

        f32x4 sacc[2];
        sacc[0] = (f32x4){0.f, 0.f, 0.f, 0.f};
        sacc[1] = (f32x4){0.f, 0.f, 0.f, 0.f};
#pragma unroll
        for (int ks = 0; ks < 4; ++ks) {
#pragma unroll
            for (int nb = 0; nb < 2; ++nb) {
                int off = (nb * 16 + l16) * PK + ks * 32 + quad * 8;
                bf16x8 kh = *(const bf16x8*)&Kh[off];
                bf16x8 kl = *(const bf16x8*)&Kl[off];
                sacc[nb] = __builtin_amdgcn_mfma_f32_16x16x32_bf16(qh[ks], kh, sacc[nb], 0, 0, 0);
                sacc[nb] = __builtin_amdgcn_mfma_f32_16x16x32_bf16(qh[ks], kl, sacc[nb], 0, 0, 0);
                sacc[nb] = __builtin_amdgcn_mfma_f32_16x16x32_bf16(ql[ks], kh, sacc[nb], 0, 0, 0);
            }
        }

        float p0[4], p1[4];
#pragma unroll
        for (int r = 0; r < 4; ++r) {
            float m0 = fmaxf(sacc[0][r], sacc[1][r]);
#pragma unroll
            for (int off = 8; off >= 1; off >>= 1)
                m0 = fmaxf(m0, __shfl_xor(m0, off, 64));
            float mnew  = fmaxf(mrow[r], m0);
            float alpha = __builtin_amdgcn_exp2f(mrow[r] - mnew);
            mrow[r] = mnew;
            float e0 = __builtin_amdgcn_exp2f(sacc[0][r] - mnew);
            float e1 = __builtin_amdgcn_exp2f(sacc[1][r] - mnew);
            p0[r] = e0; p1[r] = e1;
            Lp[r] = Lp[r] * alpha + (e0 + e1);
#pragma unroll
            for (int d = 0; d < 8; ++d) O[d][r] *= alpha;
        }

        bf16* pw = &Ps2[wave * 16 * PP];
#pragma unroll
        for (int r = 0; r < 4; ++r) {
            pw[(quad * 4 + r) * PP + l16]      = (bf16)p0[r];
            pw[(quad * 4 + r) * PP + 16 + l16] = (bf16)p1[r];
        }
        {
            bf16x8 pa = *(const bf16x8*)&pw[l16 * PP + quad * 8];
#pragma unroll
            for (int d = 0; d < 8; ++d) {
                bf16x8 vb = *(const bf16x8*)&Vs[(d * 16 + l16) * PVT + quad * 8];
                O[d] = __builtin_amdgcn_mfma_f32_16x16x32_bf16(pa, vb, O[d], 0, 0, 0);
            }
        }
    }

    float rl[4];
#pragma unroll
    for (int r = 0; r < 4; ++r) {
        float L = Lp[r];
#pragma unroll
        for (int off = 8; off >= 1; off >>= 1)
            L += __shfl_xor(L, off, 64);
        rl[r] = 1.0f / L;
    }
    float* og = out + ((size_t)bh * S_ + (size_t)qt * BM + wave * 16) * D_;
#pragma unroll
    for (int d = 0; d < 8; ++d)
#pragma unroll
        for (int r = 0; r < 4; ++r)
            og[(quad * 4 + r) * D_ + d * 16 + l16] = O[d][r] * rl[r];
}

extern "C" void kernel_launch(void* const* d_in, const int* in_sizes, int n_in,
                              void* d_out, int out_size, void* d_ws, size_t ws_size,
                              hipStream_t stream) {
    const float* q  = (const float*)d_in[0];
    const float* k  = (const float*)d_in[1];
    const float* v  = (const float*)d_in[2];
    const float* sc = (const float*)d_in[3];
    float* o = (float*)d_out;
    if (d_ws && ws_size >= WS_NEED) {
        bf16* ws = (bf16*)d_ws;
        prepack<<<16384, 256, 0, stream>>>(k, v, ws);          // ~60 us
        attn_fwd<<<2048, 256, 0, stream>>>(q, ws, sc, o);
    } else {
        attn_fwd_fb<<<dim3(S_ / BM, 64), 256, 0, stream>>>(q, k, v, sc, o);
    }
}